// Round 1
// baseline (45.232 us; speedup 1.0000x reference)
//
#include <hip/hip_runtime.h>
#include <math.h>

#define NKEYS 8192
#define NBINS 128
#define NFREQ 64
#define NKER  3
#define HEADD (2 * NFREQ)

#define KPB     16          // keys per block
#define THREADS 512         // 128 bins x 4 key-quarters
#define KPT     (KPB / 4)   // keys per thread = 4
#define LDS_STRIDE (KPB + 1) // pad to break bank conflicts on prologue writes

#if __has_builtin(__builtin_amdgcn_exp2f)
#define EXP2(x) __builtin_amdgcn_exp2f(x)
#else
#define EXP2(x) exp2f(x)
#endif

#define LOG2E 1.44269504088896340736f

// ---------------------------------------------------------------------------
// Kernel 1: precompute per-(b,f,k) params into d_ws as float4:
//   { ka*cos(mu_eff), ka*sin(mu_eff), -ka, weight }  with ka = kappa*log2(e)
// layout [f][k][b] so the main kernel's per-bin reads are lane-consecutive.
// ---------------------------------------------------------------------------
__global__ void precompute_params(const float* __restrict__ refang,
                                  const float* __restrict__ mu,
                                  const float* __restrict__ kappa,
                                  const float* __restrict__ weight,
                                  float4* __restrict__ P) {
    int o = blockIdx.x * blockDim.x + threadIdx.x;
    if (o >= NBINS * NFREQ * NKER) return;
    int b = o & (NBINS - 1);
    int fk = o >> 7;
    int f = fk / NKER;
    int k = fk - f * NKER;
    int in_idx = (b * NFREQ + f) * NKER + k;
    float me = mu[in_idx] + refang[f];
    float ka = kappa[in_idx] * LOG2E;
    float s, c;
    sincosf(me, &s, &c);
    P[o] = make_float4(ka * c, ka * s, -ka, weight[in_idx]);
}

// ---------------------------------------------------------------------------
// Kernel 2: main. Each block: 16 keys x all 128 bins.
// thread: bin = tid&127, quarter = tid>>7 -> keys quarter*4 .. quarter*4+3
// cos(angle - mu_eff) = cx*cos(mu_eff) + sy*sin(mu_eff),  cx=x/|K|, sy=y/|K|
// ---------------------------------------------------------------------------
template <bool PRECOMP>
__global__ __launch_bounds__(THREADS) void vonmises_main(
    const float* __restrict__ K,
    const float4* __restrict__ P,
    const float* __restrict__ refang,
    const float* __restrict__ mu,
    const float* __restrict__ kappa,
    const float* __restrict__ weight,
    const float* __restrict__ bias,
    float* __restrict__ out)
{
    __shared__ float4 lds[NFREQ * LDS_STRIDE]; // {cx, sy, mag, 0} at [f*LDS_STRIDE + key]

    const int tid  = threadIdx.x;
    const int key0 = blockIdx.x * KPB;

    // Prologue: stage cx/sy/mag for 16 keys x 64 freqs (1024 pairs, 2/thread).
    // Lane-consecutive f -> coalesced float2 loads of K.
    for (int p = tid; p < KPB * NFREQ; p += THREADS) {
        int key = p >> 6;      // p / NFREQ
        int f   = p & (NFREQ - 1);
        const float2 xy = *(const float2*)(K + (size_t)(key0 + key) * HEADD + 2 * f);
        float m2 = xy.x * xy.x + xy.y * xy.y;
        float rm = (m2 > 0.f) ? rsqrtf(m2) : 0.f;
        lds[f * LDS_STRIDE + key] = make_float4(xy.x * rm, xy.y * rm, m2 * rm, 0.f);
    }
    __syncthreads();

    const int bin     = tid & (NBINS - 1);
    const int quarter = tid >> 7;           // 0..3
    const int kbase   = quarter * KPT;

    float acc[KPT];
    #pragma unroll
    for (int j = 0; j < KPT; ++j) acc[j] = 0.f;

    for (int f = 0; f < NFREQ; ++f) {
        // broadcast reads (same address across each wave)
        float4 kv[KPT];
        #pragma unroll
        for (int j = 0; j < KPT; ++j)
            kv[j] = lds[f * LDS_STRIDE + kbase + j];

        float wk[KPT];
        #pragma unroll
        for (int j = 0; j < KPT; ++j) wk[j] = 0.f;

        #pragma unroll
        for (int k = 0; k < NKER; ++k) {
            float4 pp;
            if (PRECOMP) {
                pp = P[(f * NKER + k) * NBINS + bin];   // lane-consecutive, L2-hot
            } else {
                int in_idx = (bin * NFREQ + f) * NKER + k;
                float me = mu[in_idx] + refang[f];
                float ka = kappa[in_idx] * LOG2E;
                float s, c;
                __sincosf(me, &s, &c);
                pp = make_float4(ka * c, ka * s, -ka, weight[in_idx]);
            }
            #pragma unroll
            for (int j = 0; j < KPT; ++j) {
                float t = fmaf(kv[j].x, pp.x, fmaf(kv[j].y, pp.y, pp.z));
                float e = EXP2(t);
                wk[j] = fmaf(e, pp.w, wk[j]);
            }
        }

        #pragma unroll
        for (int j = 0; j < KPT; ++j)
            acc[j] = fmaf(wk[j], kv[j].z, acc[j]);   // fold magnitude once per f
    }

    const float bb = bias[bin];
    #pragma unroll
    for (int j = 0; j < KPT; ++j) {
        int key = key0 + kbase + j;
        out[(size_t)key * NBINS + bin] = acc[j] + bb;   // lane-consecutive stores
    }
}

// ---------------------------------------------------------------------------
extern "C" void kernel_launch(void* const* d_in, const int* in_sizes, int n_in,
                              void* d_out, int out_size, void* d_ws, size_t ws_size,
                              hipStream_t stream) {
    const float* K      = (const float*)d_in[0];
    const float* refang = (const float*)d_in[1];
    const float* mu     = (const float*)d_in[2];
    const float* kappa  = (const float*)d_in[3];
    const float* weight = (const float*)d_in[4];
    const float* bias   = (const float*)d_in[5];
    float* out = (float*)d_out;

    const size_t need = (size_t)NBINS * NFREQ * NKER * sizeof(float4); // 384 KiB

    if (ws_size >= need) {
        float4* P = (float4*)d_ws;
        int total = NBINS * NFREQ * NKER;
        precompute_params<<<(total + 255) / 256, 256, 0, stream>>>(refang, mu, kappa, weight, P);
        vonmises_main<true><<<NKEYS / KPB, THREADS, 0, stream>>>(
            K, P, refang, mu, kappa, weight, bias, out);
    } else {
        vonmises_main<false><<<NKEYS / KPB, THREADS, 0, stream>>>(
            K, nullptr, refang, mu, kappa, weight, bias, out);
    }
}